// Round 2
// baseline (429.398 us; speedup 1.0000x reference)
//
#include <hip/hip_runtime.h>
#include <math.h>

#define COLORS 10
#define MAX_SHIFT 5
#define NB 32
#define H 128
#define W 128
#define NS 120          // 11*11 - 1 shifts
#define HW (H*W)

typedef unsigned int u32;
typedef unsigned long long u64;

// D planes: per b, per c: 138 padded rows (yp = y+5), 6 u32 words per row.
// Pixel x lives at bit (32+x) of the 192-bit row. Margins (words 0,5 and rows
// yp<5 / yp>=133) are all-ones for c==0 (zero padding -> color 0), else 0.
#define DROW_W 6
#define DROWS 138
#define D_PER_B (COLORS * DROWS * DROW_W)      // 8280 u32
// O planes: per b, per c: 128 rows x 4 u32, pixel x at bit x.
#define OROW_W 4
#define O_PER_B (COLORS * H * OROW_W)          // 5120 u32

__global__ __launch_bounds__(256) void build_bp(
    const int* __restrict__ din, const int* __restrict__ dout,
    u32* __restrict__ D, u32* __restrict__ O)
{
    int b = blockIdx.x;
    int t = threadIdx.x;
    u32* Db = D + (size_t)b * D_PER_B;
    u32* Ob = O + (size_t)b * O_PER_B;

    // margin words (non-interior) only; interior written by ballot pass (disjoint)
    for (int w = t; w < D_PER_B; w += 256) {
        int c   = w / (DROWS * DROW_W);
        int rem = w - c * (DROWS * DROW_W);
        int yp  = rem / DROW_W;
        int wi  = rem - yp * DROW_W;
        bool interior = (yp >= 5 && yp < 133 && wi >= 1 && wi <= 4);
        if (!interior) Db[w] = (c == 0) ? 0xFFFFFFFFu : 0u;
    }

    int wave = t >> 6, lane = t & 63;
    const int* di = din  + b * HW;
    const int* dd = dout + b * HW;
    for (int task = wave; task < H * 2; task += 4) {
        int y = task >> 1, half = task & 1;
        int x = half * 64 + lane;
        int vi = di[y * W + x];
        int vo = dd[y * W + x];
        #pragma unroll
        for (int c = 0; c < COLORS; c++) {
            u64 mi = __ballot(vi == c);
            u64 mo = __ballot(vo == c);
            if (lane < 2) {
                Db[(c * DROWS + y + 5) * DROW_W + 1 + half * 2 + lane] = (u32)(mi >> (lane * 32));
                Ob[(c * H + y) * OROW_W + half * 2 + lane]             = (u32)(mo >> (lane * 32));
            }
        }
    }
}

// match[b*NS+s] = sum_c wexp[c] * popcount(shifted D_c & O_c)
__global__ __launch_bounds__(256) void match_bp(
    const u32* __restrict__ D, const u32* __restrict__ O,
    const float* __restrict__ clw, float* __restrict__ match)
{
    int s2 = blockIdx.x;            // 0..59
    int b  = blockIdx.y;
    int t  = threadIdx.x;
    int s_loc = t >> 7;             // 0..1
    int y  = t & 127;
    int s  = s2 * 2 + s_loc;
    int lin = s + (s >= 60 ? 1 : 0);
    int ddy = lin / 11 - 5, ddx = lin % 11 - 5;

    __shared__ float wexp[COLORS];
    if (t < COLORS) wexp[t] = expf(clw[t]);
    __syncthreads();

    int yp = y - ddy + 5;           // 0..137, always in range
    int p  = 32 - ddx;              // 27..37, never 0 or 64

    float acc = 0.f;
    #pragma unroll
    for (int c = 0; c < COLORS; c++) {
        const u64* dr = (const u64*)(D + ((size_t)(b * COLORS + c) * DROWS + yp) * DROW_W);
        u64 r0 = dr[0], r1 = dr[1], r2 = dr[2];
        const u64* orp = (const u64*)(O + ((size_t)(b * COLORS + c) * H + y) * OROW_W);
        u64 o0 = orp[0], o1 = orp[1];
        u64 sh0 = (r0 >> p) | (r1 << (64 - p));
        u64 sh1 = (r1 >> p) | (r2 << (64 - p));
        int cnt = __popcll(sh0 & o0) + __popcll(sh1 & o1);
        acc += wexp[c] * (float)cnt;
    }

    for (int off = 32; off > 0; off >>= 1) acc += __shfl_down(acc, off, 64);
    __shared__ float wsum[4];
    if ((t & 63) == 0) wsum[t >> 6] = acc;
    __syncthreads();
    if (t == 0)        match[b * NS + s] = wsum[0] + wsum[1];
    else if (t == 128) match[b * NS + s] = wsum[2] + wsum[3];
}

// Legacy match (fallback if ws too small for bitplanes)
__global__ __launch_bounds__(256) void match_kernel(
    const int* __restrict__ demo_in, const int* __restrict__ demo_out,
    const float* __restrict__ clw, float* __restrict__ match)
{
    int blk = blockIdx.x;
    int b = blk / NS;
    int s = blk % NS;
    int lin = s + (s >= 60 ? 1 : 0);
    int dy = lin / 11 - 5, dx = lin % 11 - 5;

    __shared__ float wexp[COLORS];
    int tid = threadIdx.x;
    if (tid < COLORS) wexp[tid] = expf(clw[tid]);
    __syncthreads();

    const int* __restrict__ din  = demo_in  + b * HW;
    const int* __restrict__ dout = demo_out + b * HW;

    float partial = 0.f;
    for (int i = tid; i < HW; i += 256) {
        int y = i >> 7, x = i & 127;
        int co = dout[i];
        int sy = y - dy, sx = x - dx;
        int v = 0;
        if (sy >= 0 && sy < H && sx >= 0 && sx < W) v = din[sy * W + sx];
        if (v == co) partial += wexp[co];
    }
    for (int off = 32; off > 0; off >>= 1) partial += __shfl_down(partial, off, 64);
    __shared__ float wsum[4];
    if ((tid & 63) == 0) wsum[tid >> 6] = partial;
    __syncthreads();
    if (tid == 0) match[blk] = wsum[0] + wsum[1] + wsum[2] + wsum[3];
}

__global__ __launch_bounds__(64) void softmax_kernel(
    const float* __restrict__ match, const float* __restrict__ logit_scale,
    float* __restrict__ attention)
{
    int b = blockIdx.x;
    int lane = threadIdx.x;
    float scale = fminf(expf(logit_scale[0]), 100.0f) / sqrtf((float)HW);

    int i0 = lane, i1 = lane + 64;
    float s0 = match[b * NS + i0] * scale;
    float s1 = (i1 < NS) ? match[b * NS + i1] * scale : -INFINITY;

    float m = fmaxf(s0, s1);
    for (int off = 32; off > 0; off >>= 1) m = fmaxf(m, __shfl_xor(m, off, 64));
    float e0 = expf(s0 - m);
    float e1 = (i1 < NS) ? expf(s1 - m) : 0.f;
    float sum = e0 + e1;
    for (int off = 32; off > 0; off >>= 1) sum += __shfl_xor(sum, off, 64);
    float inv = 1.0f / sum;
    attention[b * NS + i0] = e0 * inv;
    if (i1 < NS) attention[b * NS + i1] = e1 * inv;
}

// out[b,c,y,x] = log(max(sum_s att[b,s]*(q[y-dy,x-dx]==c), 1e-6))
// LDS scatter: each thread owns column tid of acc[10][128]; ds_add_f32
// (fire-and-forget) does the data-dependent color select in LDS addressing.
#define QP_W 144   // padded row stride (138 used)
__global__ __launch_bounds__(128) void accum_kernel(
    const int* __restrict__ query_in, const float* __restrict__ att,
    float* __restrict__ out)
{
    __shared__ int   qpad[11 * QP_W];
    __shared__ float accs[COLORS * 128];

    int t = threadIdx.x;
    int y = blockIdx.x;
    int b = blockIdx.y;
    const int* __restrict__ q = query_in + b * HW;

    // stage 11 zero-padded rows: qpad[r][px] = q[y-5+r][px-5] or 0 if OOB
    for (int r = 0; r < 11; ++r) {
        int sy = y - 5 + r;
        bool yok = (sy >= 0 && sy < H);
        {
            int px = t, sx = px - 5;
            int v = 0;
            if (yok && sx >= 0) v = q[sy * W + sx];   // sx <= 122 < W
            qpad[r * QP_W + px] = v;
        }
        if (t < 10) {
            int px = 128 + t, sx = px - 5;            // 123..132
            int v = 0;
            if (yok && sx < W) v = q[sy * W + sx];
            qpad[r * QP_W + px] = v;
        }
    }
    #pragma unroll
    for (int c = 0; c < COLORS; c++) accs[c * 128 + t] = 0.f;
    __syncthreads();

    const float* attb = att + b * NS;
    #pragma unroll
    for (int ddy = -5; ddy <= 5; ++ddy) {
        int r = 5 - ddy;            // qpad row holding sy = y - ddy
        #pragma unroll
        for (int ddx = -5; ddx <= 5; ++ddx) {
            if (ddy == 0 && ddx == 0) continue;
            int v = qpad[r * QP_W + (5 - ddx) + t];   // imm offset, vaddr = t*4
            int lin = (ddy + 5) * 11 + (ddx + 5);
            int s = lin - (lin > 60 ? 1 : 0);
            float a = attb[s];                         // wave-uniform -> s_load
            atomicAdd(&accs[v * 128 + t], a);          // ds_add_f32, no conflicts
        }
    }
    __syncthreads();

    float* __restrict__ ob = out + ((size_t)b * COLORS) * HW + y * W + t;
    #pragma unroll
    for (int c = 0; c < COLORS; c++)
        ob[(size_t)c * HW] = __logf(fmaxf(accs[c * 128 + t], 1e-6f));
}

extern "C" void kernel_launch(void* const* d_in, const int* in_sizes, int n_in,
                              void* d_out, int out_size, void* d_ws, size_t ws_size,
                              hipStream_t stream) {
    const int*   demo_in     = (const int*)d_in[0];
    const int*   demo_out    = (const int*)d_in[1];
    const int*   query_in    = (const int*)d_in[2];
    const float* clw         = (const float*)d_in[3];
    const float* logit_scale = (const float*)d_in[4];
    float* out = (float*)d_out;

    float* match     = (float*)d_ws;            // NB*NS floats
    float* attention = match + NB * NS;         // NB*NS floats
    size_t base = (size_t)(2 * NB * NS) * sizeof(float);   // 30720, 8B aligned
    u32* D = (u32*)((char*)d_ws + base);
    u32* O = D + (size_t)NB * D_PER_B;
    size_t needed = base + ((size_t)NB * D_PER_B + (size_t)NB * O_PER_B) * sizeof(u32);

    if (ws_size >= needed) {
        build_bp<<<NB, 256, 0, stream>>>(demo_in, demo_out, D, O);
        match_bp<<<dim3(NS / 2, NB), 256, 0, stream>>>(D, O, clw, match);
    } else {
        match_kernel<<<NB * NS, 256, 0, stream>>>(demo_in, demo_out, clw, match);
    }
    softmax_kernel<<<NB, 64, 0, stream>>>(match, logit_scale, attention);
    accum_kernel<<<dim3(H, NB), 128, 0, stream>>>(query_in, attention, out);
}

// Round 3
// 50.447 us; speedup vs baseline: 8.5118x; 8.5118x over previous
//
#include <hip/hip_runtime.h>
#include <hip/hip_bf16.h>
#include <math.h>

#define COLORS 10
#define NB 32
#define H 128
#define W 128
#define NS 120          // 11*11 - 1 shifts
#define HW (H*W)
#define STRIPS 8
#define SH 16           // rows per strip
#define DROWS 26        // SH + 10 padded rows
#define DINW 8          // padded din row stride in u32 (32B, b128-aligned)

typedef unsigned int u32;
typedef unsigned long long u64;
typedef float f32x4 __attribute__((ext_vector_type(4)));
typedef short bf16x8 __attribute__((ext_vector_type(8)));

// ---------------- match: per-(b,strip) bitplane popcount ----------------
// Padded demo_in planes: pbit = x+5 (bits 0..137 valid); color-0 margins = 1
// encode zero-padding (OOB -> color 0). demo_out planes: bit = x.
__global__ __launch_bounds__(256) void match_strip(
    const int* __restrict__ demo_in, const int* __restrict__ demo_out,
    const float* __restrict__ clw, float* __restrict__ mpart)
{
    __shared__ u32 din_p[COLORS][DROWS][DINW];
    __shared__ u32 dout_p[COLORS][SH][4];
    __shared__ float wexp[COLORS];
    __shared__ float pp[128];

    int t = threadIdx.x;
    int strip = blockIdx.x;
    int b = blockIdx.y;
    int wave = t >> 6, lane = t & 63;

    if (t < COLORS) wexp[t] = __expf(clw[t]);

    const int* di = demo_in  + b * HW;
    const int* dd = demo_out + b * HW;
    int y0 = strip * SH;

    // build padded demo_in planes, rows r=0..25 (global gy = y0-5+r)
    for (int r = wave; r < DROWS; r += 4) {
        int gy = y0 - 5 + r;
        bool ok = (gy >= 0 && gy < H);
        int v0 = 0, v1 = 0;
        if (ok) { v0 = di[gy * W + lane]; v1 = di[gy * W + 64 + lane]; }
        #pragma unroll
        for (int c = 0; c < COLORS; c++) {
            u64 h0 = __ballot(v0 == c);
            u64 h1 = __ballot(v1 == c);
            u64 P0, P1, P2;
            if (!ok) {                      // whole row OOB -> color 0
                P0 = (c == 0) ? ~0ull : 0ull;
                P1 = P0;
                P2 = (c == 0) ? 0x3FFull : 0ull;          // pbits 128..137
            } else {
                u64 lm = (c == 0) ? 0x1Full  : 0ull;      // pbits 0..4
                u64 rm = (c == 0) ? 0x3E0ull : 0ull;      // pbits 133..137
                P0 = (h0 << 5) | lm;
                P1 = (h0 >> 59) | (h1 << 5);
                P2 = (h1 >> 59) | rm;
            }
            if (lane == 0) {
                u32* w = &din_p[c][r][0];
                w[0] = (u32)P0; w[1] = (u32)(P0 >> 32);
                w[2] = (u32)P1; w[3] = (u32)(P1 >> 32);
                w[4] = (u32)P2; w[5] = 0; w[6] = 0; w[7] = 0;
            }
        }
    }
    // demo_out planes rows 0..15
    for (int r = wave; r < SH; r += 4) {
        int gy = y0 + r;
        int v0 = dd[gy * W + lane], v1 = dd[gy * W + 64 + lane];
        #pragma unroll
        for (int c = 0; c < COLORS; c++) {
            u64 h0 = __ballot(v0 == c);
            u64 h1 = __ballot(v1 == c);
            if (lane == 0) {
                u32* w = &dout_p[c][r][0];
                w[0] = (u32)h0; w[1] = (u32)(h0 >> 32);
                w[2] = (u32)h1; w[3] = (u32)(h1 >> 32);
            }
        }
    }
    __syncthreads();

    int s  = t & 127;
    int yh = t >> 7;          // each thread does 8 of the 16 rows
    float acc = 0.f;
    if (s < NS) {
        int lin = s + (s >= 60);
        int dy = lin / 11 - 5, dx = lin % 11 - 5;
        int k = 5 - dx;       // 0..10
        for (int c = 0; c < COLORS; c++) {
            int cnt = 0;
            #pragma unroll
            for (int yy = 0; yy < 8; yy++) {
                int y = yh * 8 + yy;
                int r = y - dy + 5;                     // 0..25
                const u32* dr   = &din_p[c][r][0];
                const u32* orow = &dout_p[c][y][0];
                u32 s0 = __builtin_amdgcn_alignbit(dr[1], dr[0], k);
                u32 s1 = __builtin_amdgcn_alignbit(dr[2], dr[1], k);
                u32 s2 = __builtin_amdgcn_alignbit(dr[3], dr[2], k);
                u32 s3 = __builtin_amdgcn_alignbit(dr[4], dr[3], k);
                cnt += __popc(s0 & orow[0]) + __popc(s1 & orow[1])
                     + __popc(s2 & orow[2]) + __popc(s3 & orow[3]);
            }
            acc += wexp[c] * (float)cnt;
        }
    }
    if (yh == 1) pp[s] = acc;
    __syncthreads();
    if (yh == 0 && s < NS)
        mpart[(b * NS + s) * STRIPS + strip] = acc + pp[s];
}

// ------------- softmax over shifts + A-fragment build (per b) -------------
__global__ __launch_bounds__(64) void softmax_abuild(
    const float* __restrict__ mpart, const float* __restrict__ logit_scale,
    float* __restrict__ attention, u32* __restrict__ Ag)
{
    __shared__ float sm[NS];
    int b = blockIdx.x;
    int l = threadIdx.x;
    float scale = fminf(__expf(logit_scale[0]), 100.0f) * (1.0f / 128.0f);

    float s0v, s1v;
    {
        const float* mp = mpart + (b * NS + l) * STRIPS;
        float a = 0;
        #pragma unroll
        for (int i = 0; i < STRIPS; i++) a += mp[i];
        s0v = a * scale;
    }
    int i1 = l + 64;
    if (i1 < NS) {
        const float* mp = mpart + (b * NS + i1) * STRIPS;
        float a = 0;
        #pragma unroll
        for (int i = 0; i < STRIPS; i++) a += mp[i];
        s1v = a * scale;
    } else s1v = -INFINITY;

    float m = fmaxf(s0v, s1v);
    for (int off = 32; off > 0; off >>= 1) m = fmaxf(m, __shfl_xor(m, off, 64));
    float e0 = __expf(s0v - m);
    float e1 = (i1 < NS) ? __expf(s1v - m) : 0.f;
    float sum = e0 + e1;
    for (int off = 32; off > 0; off >>= 1) sum += __shfl_xor(sum, off, 64);
    float inv = 1.0f / sum;
    float a0 = e0 * inv;
    attention[b * NS + l] = a0;
    sm[l] = a0;
    if (i1 < NS) { float a1 = e1 * inv; attention[b * NS + i1] = a1; sm[i1] = a1; }
    __syncthreads();

    // A[m][k=(st,cc)] = att(dy=5-st, dx=m+5-cc) in 16x16x32 A-fragment layout:
    // lane l: row m = l&15, k-group g = l>>4 (8 elems), bf16 pairs packed LE.
    int mrow = l & 15, g8 = (l >> 4) * 8;
    for (int st = 0; st < 11; st++) {
        int dy = 5 - st;
        u32 wq[4];
        #pragma unroll
        for (int p = 0; p < 4; p++) {
            u32 wv = 0;
            #pragma unroll
            for (int hh = 0; hh < 2; hh++) {
                int cc = g8 + p * 2 + hh;
                int dx = mrow + 5 - cc;
                unsigned short hv = 0;
                if (dx >= -5 && dx <= 5 && !(dy == 0 && dx == 0)) {
                    int lin = (dy + 5) * 11 + (dx + 5);
                    int si = lin - (lin > 60);
                    __hip_bfloat16 hb = __float2bfloat16(sm[si]);
                    hv = *reinterpret_cast<unsigned short*>(&hb);
                }
                wv |= ((u32)hv) << (16 * hh);
            }
            wq[p] = wv;
        }
        *reinterpret_cast<uint4*>(Ag + ((size_t)(b * 11 + st) * 64 + l) * 4) =
            make_uint4(wq[0], wq[1], wq[2], wq[3]);
    }
}

// --------------------- accum via MFMA 16x16x32 bf16 ---------------------
// Block = (y, b). D[m=16 px, n=16 c] = sum_k A[m,k] * B[k,c], k = 11x32 cells.
__global__ __launch_bounds__(256) void accum_mfma(
    const int* __restrict__ query_in, const u32* __restrict__ Ag,
    float* __restrict__ out)
{
    __shared__ __align__(16) int qs[11][144];   // qs[r][p] = q[y-5+r][p-5] or 0
    int t = threadIdx.x;
    int y = blockIdx.x;
    int b = blockIdx.y;
    const int* q = query_in + b * HW;

    for (int r = 0; r < 11; r++) {
        int gy = y - 5 + r;
        bool ok = (gy >= 0 && gy < H);
        for (int p = t; p < 144; p += 256) {
            int v = 0;
            if (ok && p >= 5 && p < 133) v = q[gy * W + p - 5];
            qs[r][p] = v;
        }
    }

    int lane = t & 63, wv = t >> 6;
    int c = lane & 15, g = lane >> 4;

    uint4 afr[11];
    #pragma unroll
    for (int st = 0; st < 11; st++)
        afr[st] = *reinterpret_cast<const uint4*>(
            Ag + ((size_t)(b * 11 + st) * 64 + lane) * 4);

    __syncthreads();

    for (int ti = 0; ti < 2; ti++) {
        int x0 = (wv + ti * 4) * 16;
        f32x4 acc = {0.f, 0.f, 0.f, 0.f};
        #pragma unroll
        for (int st = 0; st < 11; st++) {
            uint4 qa = *reinterpret_cast<const uint4*>(&qs[st][x0 + 8 * g]);
            uint4 qb = *reinterpret_cast<const uint4*>(&qs[st][x0 + 8 * g + 4]);
            u32 b0 = ((int)qa.x == c ? 0x3F80u : 0u) | ((int)qa.y == c ? 0x3F800000u : 0u);
            u32 b1 = ((int)qa.z == c ? 0x3F80u : 0u) | ((int)qa.w == c ? 0x3F800000u : 0u);
            u32 b2 = ((int)qb.x == c ? 0x3F80u : 0u) | ((int)qb.y == c ? 0x3F800000u : 0u);
            u32 b3 = ((int)qb.z == c ? 0x3F80u : 0u) | ((int)qb.w == c ? 0x3F800000u : 0u);
            union { uint4 u; bf16x8 v; } A, B;
            A.u = afr[st];
            B.u = make_uint4(b0, b1, b2, b3);
            acc = __builtin_amdgcn_mfma_f32_16x16x32_bf16(A.v, B.v, acc, 0, 0, 0);
        }
        if (c < COLORS) {
            float* ob = out + (((size_t)b * COLORS + c) * H + y) * W + x0 + 4 * g;
            float4 r;
            r.x = __logf(fmaxf(acc[0], 1e-6f));
            r.y = __logf(fmaxf(acc[1], 1e-6f));
            r.z = __logf(fmaxf(acc[2], 1e-6f));
            r.w = __logf(fmaxf(acc[3], 1e-6f));
            *reinterpret_cast<float4*>(ob) = r;
        }
    }
}

// ----------------------- round-1 fallback kernels -----------------------
__global__ __launch_bounds__(256) void match_kernel(
    const int* __restrict__ demo_in, const int* __restrict__ demo_out,
    const float* __restrict__ clw, float* __restrict__ match)
{
    int blk = blockIdx.x;
    int b = blk / NS;
    int s = blk % NS;
    int lin = s + (s >= 60 ? 1 : 0);
    int dy = lin / 11 - 5, dx = lin % 11 - 5;

    __shared__ float wexp[COLORS];
    int tid = threadIdx.x;
    if (tid < COLORS) wexp[tid] = expf(clw[tid]);
    __syncthreads();

    const int* __restrict__ din  = demo_in  + b * HW;
    const int* __restrict__ dout = demo_out + b * HW;

    float partial = 0.f;
    for (int i = tid; i < HW; i += 256) {
        int yy = i >> 7, xx = i & 127;
        int co = dout[i];
        int sy = yy - dy, sx = xx - dx;
        int v = 0;
        if (sy >= 0 && sy < H && sx >= 0 && sx < W) v = din[sy * W + sx];
        if (v == co) partial += wexp[co];
    }
    for (int off = 32; off > 0; off >>= 1) partial += __shfl_down(partial, off, 64);
    __shared__ float wsum[4];
    if ((tid & 63) == 0) wsum[tid >> 6] = partial;
    __syncthreads();
    if (tid == 0) match[blk] = wsum[0] + wsum[1] + wsum[2] + wsum[3];
}

__global__ __launch_bounds__(64) void softmax_kernel(
    const float* __restrict__ match, const float* __restrict__ logit_scale,
    float* __restrict__ attention)
{
    int b = blockIdx.x;
    int lane = threadIdx.x;
    float scale = fminf(expf(logit_scale[0]), 100.0f) / sqrtf((float)HW);
    int i0 = lane, i1 = lane + 64;
    float s0 = match[b * NS + i0] * scale;
    float s1 = (i1 < NS) ? match[b * NS + i1] * scale : -INFINITY;
    float m = fmaxf(s0, s1);
    for (int off = 32; off > 0; off >>= 1) m = fmaxf(m, __shfl_xor(m, off, 64));
    float e0 = expf(s0 - m);
    float e1 = (i1 < NS) ? expf(s1 - m) : 0.f;
    float sum = e0 + e1;
    for (int off = 32; off > 0; off >>= 1) sum += __shfl_xor(sum, off, 64);
    float inv = 1.0f / sum;
    attention[b * NS + i0] = e0 * inv;
    if (i1 < NS) attention[b * NS + i1] = e1 * inv;
}

__global__ __launch_bounds__(128) void accum_kernel(
    const int* __restrict__ query_in, const float* __restrict__ attention,
    float* __restrict__ out)
{
    int blk = blockIdx.x;
    int b = blk >> 7;
    int y = blk & 127;
    int x = threadIdx.x;

    __shared__ float att[NS];
    if (threadIdx.x < NS) att[threadIdx.x] = attention[b * NS + threadIdx.x];
    __syncthreads();

    const int* __restrict__ q = query_in + b * HW;
    float acc[COLORS];
    #pragma unroll
    for (int c = 0; c < COLORS; c++) acc[c] = 0.f;

    #pragma unroll 4
    for (int s = 0; s < NS; s++) {
        int lin = s + (s >= 60 ? 1 : 0);
        int dy = lin / 11 - 5, dx = lin % 11 - 5;
        int sy = y - dy, sx = x - dx;
        int v = 0;
        if (sy >= 0 && sy < H && sx >= 0 && sx < W) v = q[sy * W + sx];
        float a = att[s];
        #pragma unroll
        for (int c = 0; c < COLORS; c++) acc[c] += (v == c) ? a : 0.f;
    }
    float* __restrict__ ob = out + (size_t)b * COLORS * HW + y * W + x;
    #pragma unroll
    for (int c = 0; c < COLORS; c++) ob[c * HW] = __logf(fmaxf(acc[c], 1e-6f));
}

extern "C" void kernel_launch(void* const* d_in, const int* in_sizes, int n_in,
                              void* d_out, int out_size, void* d_ws, size_t ws_size,
                              hipStream_t stream) {
    const int*   demo_in     = (const int*)d_in[0];
    const int*   demo_out    = (const int*)d_in[1];
    const int*   query_in    = (const int*)d_in[2];
    const float* clw         = (const float*)d_in[3];
    const float* logit_scale = (const float*)d_in[4];
    float* out = (float*)d_out;

    size_t mpart_sz = (size_t)NB * NS * STRIPS * 4;          // 122880
    size_t att_off  = mpart_sz;                              // +15360
    size_t ag_off   = att_off + (size_t)NB * NS * 4;         // = 138240
    size_t needed   = ag_off + (size_t)NB * 11 * 64 * 16;    // = 498688

    if (ws_size >= needed) {
        float* mpart = (float*)d_ws;
        float* att   = (float*)((char*)d_ws + att_off);
        u32*   Ag    = (u32*)((char*)d_ws + ag_off);
        match_strip<<<dim3(STRIPS, NB), 256, 0, stream>>>(demo_in, demo_out, clw, mpart);
        softmax_abuild<<<NB, 64, 0, stream>>>(mpart, logit_scale, att, Ag);
        accum_mfma<<<dim3(H, NB), 256, 0, stream>>>(query_in, Ag, out);
    } else {
        float* match = (float*)d_ws;
        float* att   = match + NB * NS;
        match_kernel<<<NB * NS, 256, 0, stream>>>(demo_in, demo_out, clw, match);
        softmax_kernel<<<NB, 64, 0, stream>>>(match, logit_scale, att);
        accum_kernel<<<NB * H, 128, 0, stream>>>(query_in, att, out);
    }
}

// Round 4
// 36.601 us; speedup vs baseline: 11.7318x; 1.3783x over previous
//
#include <hip/hip_runtime.h>
#include <hip/hip_bf16.h>
#include <math.h>

#define COLORS 10
#define NB 32
#define H 128
#define W 128
#define NS 120          // 11*11 - 1 shifts
#define HW (H*W)
#define STRIPS 8
#define SH 16           // rows per strip
#define DROWS 26        // SH + 10 padded rows
#define DINW 8          // padded din row stride in u32

typedef unsigned int u32;
typedef unsigned long long u64;
typedef float f32x4 __attribute__((ext_vector_type(4)));
typedef short bf16x8 __attribute__((ext_vector_type(8)));

// ---------------- match: per-(b,strip) bitplane popcount ----------------
__global__ __launch_bounds__(256) void match_strip(
    const int* __restrict__ demo_in, const int* __restrict__ demo_out,
    const float* __restrict__ clw, float* __restrict__ mpart)
{
    __shared__ u32 din_p[COLORS][DROWS][DINW];
    __shared__ u32 dout_p[COLORS][SH][4];
    __shared__ float wexp[COLORS];
    __shared__ float pp[128];

    int t = threadIdx.x;
    int strip = blockIdx.x;
    int b = blockIdx.y;
    int wave = t >> 6, lane = t & 63;

    if (t < COLORS) wexp[t] = __expf(clw[t]);

    const int* di = demo_in  + b * HW;
    const int* dd = demo_out + b * HW;
    int y0 = strip * SH;

    for (int r = wave; r < DROWS; r += 4) {
        int gy = y0 - 5 + r;
        bool ok = (gy >= 0 && gy < H);
        int v0 = 0, v1 = 0;
        if (ok) { v0 = di[gy * W + lane]; v1 = di[gy * W + 64 + lane]; }
        #pragma unroll
        for (int c = 0; c < COLORS; c++) {
            u64 h0 = __ballot(v0 == c);
            u64 h1 = __ballot(v1 == c);
            u64 P0, P1, P2;
            if (!ok) {
                P0 = (c == 0) ? ~0ull : 0ull;
                P1 = P0;
                P2 = (c == 0) ? 0x3FFull : 0ull;
            } else {
                u64 lm = (c == 0) ? 0x1Full  : 0ull;
                u64 rm = (c == 0) ? 0x3E0ull : 0ull;
                P0 = (h0 << 5) | lm;
                P1 = (h0 >> 59) | (h1 << 5);
                P2 = (h1 >> 59) | rm;
            }
            if (lane == 0) {
                u32* w = &din_p[c][r][0];
                w[0] = (u32)P0; w[1] = (u32)(P0 >> 32);
                w[2] = (u32)P1; w[3] = (u32)(P1 >> 32);
                w[4] = (u32)P2; w[5] = 0; w[6] = 0; w[7] = 0;
            }
        }
    }
    for (int r = wave; r < SH; r += 4) {
        int gy = y0 + r;
        int v0 = dd[gy * W + lane], v1 = dd[gy * W + 64 + lane];
        #pragma unroll
        for (int c = 0; c < COLORS; c++) {
            u64 h0 = __ballot(v0 == c);
            u64 h1 = __ballot(v1 == c);
            if (lane == 0) {
                u32* w = &dout_p[c][r][0];
                w[0] = (u32)h0; w[1] = (u32)(h0 >> 32);
                w[2] = (u32)h1; w[3] = (u32)(h1 >> 32);
            }
        }
    }
    __syncthreads();

    int s  = t & 127;
    int yh = t >> 7;
    float acc = 0.f;
    if (s < NS) {
        int lin = s + (s >= 60);
        int dy = lin / 11 - 5, dx = lin % 11 - 5;
        int k = 5 - dx;
        for (int c = 0; c < COLORS; c++) {
            int cnt = 0;
            #pragma unroll
            for (int yy = 0; yy < 8; yy++) {
                int y = yh * 8 + yy;
                int r = y - dy + 5;
                const u32* dr   = &din_p[c][r][0];
                const u32* orow = &dout_p[c][y][0];
                u32 s0 = __builtin_amdgcn_alignbit(dr[1], dr[0], k);
                u32 s1 = __builtin_amdgcn_alignbit(dr[2], dr[1], k);
                u32 s2 = __builtin_amdgcn_alignbit(dr[3], dr[2], k);
                u32 s3 = __builtin_amdgcn_alignbit(dr[4], dr[3], k);
                cnt += __popc(s0 & orow[0]) + __popc(s1 & orow[1])
                     + __popc(s2 & orow[2]) + __popc(s3 & orow[3]);
            }
            acc += wexp[c] * (float)cnt;
        }
    }
    if (yh == 1) pp[s] = acc;
    __syncthreads();
    if (yh == 0 && s < NS)
        mpart[(b * NS + s) * STRIPS + strip] = acc + pp[s];
}

// ------------- softmax + A-fragment build (per b), 4 waves -------------
__global__ __launch_bounds__(256) void softmax_abuild(
    const float* __restrict__ mpart, const float* __restrict__ logit_scale,
    u32* __restrict__ Ag)
{
    __shared__ float sm[NS];      // scores
    __shared__ float sa[NS];      // attention
    int b = blockIdx.x;
    int t = threadIdx.x;
    float scale = fminf(__expf(logit_scale[0]), 100.0f) * (1.0f / 128.0f);

    if (t < NS) {
        const float* mp = mpart + (b * NS + t) * STRIPS;
        float a = 0;
        #pragma unroll
        for (int i = 0; i < STRIPS; i++) a += mp[i];
        sm[t] = a * scale;
    }
    __syncthreads();

    if (t < 64) {
        int l = t;
        float s0 = sm[l];
        float s1 = (l + 64 < NS) ? sm[l + 64] : -INFINITY;
        float m = fmaxf(s0, s1);
        for (int off = 32; off > 0; off >>= 1) m = fmaxf(m, __shfl_xor(m, off, 64));
        float e0 = __expf(s0 - m);
        float e1 = (l + 64 < NS) ? __expf(s1 - m) : 0.f;
        float sum = e0 + e1;
        for (int off = 32; off > 0; off >>= 1) sum += __shfl_xor(sum, off, 64);
        float inv = 1.0f / sum;
        sa[l] = e0 * inv;
        if (l + 64 < NS) sa[l + 64] = e1 * inv;
    }
    __syncthreads();

    // A[m][k=(st,cc)] = att(dy=5-st, dx=m+5-cc), 16x16x32 A-fragment layout.
    int wv = t >> 6, lane = t & 63;
    int mrow = lane & 15, g8 = (lane >> 4) * 8;
    for (int st = wv; st < 11; st += 4) {
        int dy = 5 - st;
        u32 wq[4];
        #pragma unroll
        for (int p = 0; p < 4; p++) {
            u32 wvv = 0;
            #pragma unroll
            for (int hh = 0; hh < 2; hh++) {
                int cc = g8 + p * 2 + hh;
                int dx = mrow + 5 - cc;
                unsigned short hv = 0;
                if (dx >= -5 && dx <= 5 && !(dy == 0 && dx == 0)) {
                    int lin = (dy + 5) * 11 + (dx + 5);
                    int si = lin - (lin > 60);
                    __hip_bfloat16 hb = __float2bfloat16(sa[si]);
                    hv = *reinterpret_cast<unsigned short*>(&hb);
                }
                wvv |= ((u32)hv) << (16 * hh);
            }
            wq[p] = wvv;
        }
        *reinterpret_cast<uint4*>(Ag + ((size_t)(b * 11 + st) * 64 + lane) * 4) =
            make_uint4(wq[0], wq[1], wq[2], wq[3]);
    }
}

// --------------- accum via MFMA, y-tile of 4 rows per block ---------------
// Block (ytile, b): out rows y0..y0+3, all 128 cols, 10 colors.
// D[m=16 px, n=16 c] = sum_k A[m,k]*B[k,c]; B fragments (14 padded rows) are
// built ONCE into registers and reused across the 4 output rows.
__global__ __launch_bounds__(256) void accum_mfma(
    const int* __restrict__ query_in, const u32* __restrict__ Ag,
    float* __restrict__ out)
{
    __shared__ __align__(16) int qs[14][144];   // qs[r][p] = q[y0-5+r][p-5] or 0
    int t = threadIdx.x;
    int y0 = blockIdx.x * 4;
    int b  = blockIdx.y;
    const int* q = query_in + b * HW;

    // batched staging: 14*144 = 2016 words; all loads issued back-to-back
    int vstage[8];
    #pragma unroll
    for (int i = 0; i < 8; i++) {
        int idx = t + i * 256;
        int r = idx / 144;
        int p = idx - r * 144;
        int gy = y0 - 5 + r;
        bool ok = (idx < 2016) & (gy >= 0) & (gy < H) & (p >= 5) & (p < 133);
        int cy = gy < 0 ? 0 : (gy > 127 ? 127 : gy);
        int cx = p < 5 ? 0 : (p > 132 ? 127 : p - 5);
        int ld = q[cy * W + cx];
        vstage[i] = ok ? ld : 0;
    }

    int lane = t & 63, wv = t >> 6;
    uint4 afr[11];
    #pragma unroll
    for (int st = 0; st < 11; st++)
        afr[st] = *reinterpret_cast<const uint4*>(
            Ag + ((size_t)(b * 11 + st) * 64 + lane) * 4);

    #pragma unroll
    for (int i = 0; i < 8; i++) {
        int idx = t + i * 256;
        if (idx < 2016) ((int*)qs)[idx] = vstage[i];
    }
    __syncthreads();

    int c = lane & 15, g = lane >> 4;

    #pragma unroll
    for (int ti = 0; ti < 2; ti++) {
        int x0 = wv * 32 + ti * 16;

        // build 14 B fragments once (window rows r=0..13 for this x0)
        uint4 bf[14];
        #pragma unroll
        for (int r = 0; r < 14; r++) {
            uint4 qa = *reinterpret_cast<const uint4*>(&qs[r][x0 + 8 * g]);
            uint4 qb = *reinterpret_cast<const uint4*>(&qs[r][x0 + 8 * g + 4]);
            u32 b0 = ((int)qa.x == c ? 0x3F80u : 0u) | ((int)qa.y == c ? 0x3F800000u : 0u);
            u32 b1 = ((int)qa.z == c ? 0x3F80u : 0u) | ((int)qa.w == c ? 0x3F800000u : 0u);
            u32 b2 = ((int)qb.x == c ? 0x3F80u : 0u) | ((int)qb.y == c ? 0x3F800000u : 0u);
            u32 b3 = ((int)qb.z == c ? 0x3F80u : 0u) | ((int)qb.w == c ? 0x3F800000u : 0u);
            bf[r] = make_uint4(b0, b1, b2, b3);
        }

        f32x4 acc[4];
        #pragma unroll
        for (int j = 0; j < 4; j++) acc[j] = (f32x4){0.f, 0.f, 0.f, 0.f};

        #pragma unroll
        for (int st = 0; st < 11; st++) {
            #pragma unroll
            for (int j = 0; j < 4; j++) {
                union { uint4 u; bf16x8 v; } A, B;
                A.u = afr[st];
                B.u = bf[st + j];
                acc[j] = __builtin_amdgcn_mfma_f32_16x16x32_bf16(A.v, B.v, acc[j], 0, 0, 0);
            }
        }

        if (c < COLORS) {
            #pragma unroll
            for (int j = 0; j < 4; j++) {
                float* ob = out + (((size_t)b * COLORS + c) * H + (y0 + j)) * W + x0 + 4 * g;
                float4 rr;
                rr.x = __logf(fmaxf(acc[j][0], 1e-6f));
                rr.y = __logf(fmaxf(acc[j][1], 1e-6f));
                rr.z = __logf(fmaxf(acc[j][2], 1e-6f));
                rr.w = __logf(fmaxf(acc[j][3], 1e-6f));
                *reinterpret_cast<float4*>(ob) = rr;
            }
        }
    }
}

// ----------------------- round-1 fallback kernels -----------------------
__global__ __launch_bounds__(256) void match_kernel(
    const int* __restrict__ demo_in, const int* __restrict__ demo_out,
    const float* __restrict__ clw, float* __restrict__ match)
{
    int blk = blockIdx.x;
    int b = blk / NS;
    int s = blk % NS;
    int lin = s + (s >= 60 ? 1 : 0);
    int dy = lin / 11 - 5, dx = lin % 11 - 5;

    __shared__ float wexp[COLORS];
    int tid = threadIdx.x;
    if (tid < COLORS) wexp[tid] = expf(clw[tid]);
    __syncthreads();

    const int* __restrict__ din  = demo_in  + b * HW;
    const int* __restrict__ dout = demo_out + b * HW;

    float partial = 0.f;
    for (int i = tid; i < HW; i += 256) {
        int yy = i >> 7, xx = i & 127;
        int co = dout[i];
        int sy = yy - dy, sx = xx - dx;
        int v = 0;
        if (sy >= 0 && sy < H && sx >= 0 && sx < W) v = din[sy * W + sx];
        if (v == co) partial += wexp[co];
    }
    for (int off = 32; off > 0; off >>= 1) partial += __shfl_down(partial, off, 64);
    __shared__ float wsum[4];
    if ((tid & 63) == 0) wsum[tid >> 6] = partial;
    __syncthreads();
    if (tid == 0) match[blk] = wsum[0] + wsum[1] + wsum[2] + wsum[3];
}

__global__ __launch_bounds__(64) void softmax_kernel(
    const float* __restrict__ match, const float* __restrict__ logit_scale,
    float* __restrict__ attention)
{
    int b = blockIdx.x;
    int lane = threadIdx.x;
    float scale = fminf(expf(logit_scale[0]), 100.0f) / sqrtf((float)HW);
    int i0 = lane, i1 = lane + 64;
    float s0 = match[b * NS + i0] * scale;
    float s1 = (i1 < NS) ? match[b * NS + i1] * scale : -INFINITY;
    float m = fmaxf(s0, s1);
    for (int off = 32; off > 0; off >>= 1) m = fmaxf(m, __shfl_xor(m, off, 64));
    float e0 = expf(s0 - m);
    float e1 = (i1 < NS) ? expf(s1 - m) : 0.f;
    float sum = e0 + e1;
    for (int off = 32; off > 0; off >>= 1) sum += __shfl_xor(sum, off, 64);
    float inv = 1.0f / sum;
    attention[b * NS + i0] = e0 * inv;
    if (i1 < NS) attention[b * NS + i1] = e1 * inv;
}

__global__ __launch_bounds__(128) void accum_kernel(
    const int* __restrict__ query_in, const float* __restrict__ attention,
    float* __restrict__ out)
{
    int blk = blockIdx.x;
    int b = blk >> 7;
    int y = blk & 127;
    int x = threadIdx.x;

    __shared__ float att[NS];
    if (threadIdx.x < NS) att[threadIdx.x] = attention[b * NS + threadIdx.x];
    __syncthreads();

    const int* __restrict__ q = query_in + b * HW;
    float acc[COLORS];
    #pragma unroll
    for (int c = 0; c < COLORS; c++) acc[c] = 0.f;

    #pragma unroll 4
    for (int s = 0; s < NS; s++) {
        int lin = s + (s >= 60 ? 1 : 0);
        int dy = lin / 11 - 5, dx = lin % 11 - 5;
        int sy = y - dy, sx = x - dx;
        int v = 0;
        if (sy >= 0 && sy < H && sx >= 0 && sx < W) v = q[sy * W + sx];
        float a = att[s];
        #pragma unroll
        for (int c = 0; c < COLORS; c++) acc[c] += (v == c) ? a : 0.f;
    }
    float* __restrict__ ob = out + (size_t)b * COLORS * HW + y * W + x;
    #pragma unroll
    for (int c = 0; c < COLORS; c++) ob[c * HW] = __logf(fmaxf(acc[c], 1e-6f));
}

extern "C" void kernel_launch(void* const* d_in, const int* in_sizes, int n_in,
                              void* d_out, int out_size, void* d_ws, size_t ws_size,
                              hipStream_t stream) {
    const int*   demo_in     = (const int*)d_in[0];
    const int*   demo_out    = (const int*)d_in[1];
    const int*   query_in    = (const int*)d_in[2];
    const float* clw         = (const float*)d_in[3];
    const float* logit_scale = (const float*)d_in[4];
    float* out = (float*)d_out;

    size_t mpart_sz = (size_t)NB * NS * STRIPS * 4;
    size_t att_off  = mpart_sz;
    size_t ag_off   = att_off + (size_t)NB * NS * 4;
    size_t needed   = ag_off + (size_t)NB * 11 * 64 * 16;

    if (ws_size >= needed) {
        float* mpart = (float*)d_ws;
        u32*   Ag    = (u32*)((char*)d_ws + ag_off);
        match_strip<<<dim3(STRIPS, NB), 256, 0, stream>>>(demo_in, demo_out, clw, mpart);
        softmax_abuild<<<NB, 256, 0, stream>>>(mpart, logit_scale, Ag);
        accum_mfma<<<dim3(H / 4, NB), 256, 0, stream>>>(query_in, Ag, out);
    } else {
        float* match = (float*)d_ws;
        float* att   = match + NB * NS;
        match_kernel<<<NB * NS, 256, 0, stream>>>(demo_in, demo_out, clw, match);
        softmax_kernel<<<NB, 64, 0, stream>>>(match, logit_scale, att);
        accum_kernel<<<NB * H, 128, 0, stream>>>(query_in, att, out);
    }
}